// Round 4
// baseline (1175.045 us; speedup 1.0000x reference)
//
#include <hip/hip_runtime.h>

#define BROWS 32768
#define DIM   512
#define NK    1024
#define NL    4

// fp16 split-GEMM: x = h + l*2^-12, h = fp16(x), l = fp16((x-h)*4096) (exact scale).
// dot = sum(ha*hb) + 2^-12 * sum(ha*lb + la*hb); dropped la*lb ~ 2^-24 relative.
// Limb storage is PER-ROW INTERLEAVED: row r = [h x512 | l x512] f16, stride
// 2048 B. Residual limbs live in the q output buffer (row r limbs occupy the
// exact bytes Q row r later overwrites -> per-thread read-all-first is safe).
typedef _Float16 f16;
typedef _Float16 f16x8 __attribute__((ext_vector_type(8)));
typedef float f32x4 __attribute__((ext_vector_type(4)));

#define LSC 2.44140625e-4f  // 2^-12

union H4 { f16 h[4]; ushort4 u; };

__device__ __forceinline__ void split2(float x, f16& h, f16& l) {
  h = (f16)x;                           // RNE, 11-bit significand
  l = (f16)((x - (float)h) * 4096.0f);  // exact diff, exact scale
}

__device__ __forceinline__ void gload16(const void* g, const void* l) {
  __builtin_amdgcn_global_load_lds(
      (const __attribute__((address_space(1))) void*)g,
      (__attribute__((address_space(3))) void*)l, 16, 0, 0);
}

// ---------------------------------------------------------------------------
// k_pre: c2 for all 4096 codes (fp32, exact) + interleaved fp16 limb codebook.
// ---------------------------------------------------------------------------
__global__ __launch_bounds__(64) void k_pre(const float* __restrict__ cb,
                                            float* __restrict__ c2all,
                                            float* __restrict__ loss_slot,
                                            f16* __restrict__ cbI) {
  const int code = blockIdx.x;           // 0..4095
  const int lane = threadIdx.x;          // 0..63
  const float4* c4 = (const float4*)(cb + (size_t)code * DIM);
  f16* rowL = cbI + (size_t)code * 1024;  // [h 512 | l 512]
  float s = 0.f;
#pragma unroll
  for (int j = 0; j < 2; ++j) {
    const int e = lane + j * 64;
    const float4 v = c4[e];
    s += v.x * v.x + v.y * v.y + v.z * v.z + v.w * v.w;
    H4 hh, ll;
#pragma unroll
    for (int c = 0; c < 4; ++c) split2((&v.x)[c], hh.h[c], ll.h[c]);
    *(ushort4*)(rowL + e * 4) = hh.u;
    *(ushort4*)(rowL + 512 + e * 4) = ll.u;
  }
#pragma unroll
  for (int m = 1; m < 64; m <<= 1) s += __shfl_xor(s, m, 64);
  if (lane == 0) c2all[code] = s;
  if (code == 0 && lane == 0) *loss_slot = 0.f;
}

// ---------------------------------------------------------------------------
// k_splitz: r2[row] = ||z_row||^2 (fp32) + interleaved fp16 limbs of z.
// ---------------------------------------------------------------------------
__global__ __launch_bounds__(256) void k_splitz(const float* __restrict__ Z,
                                                float* __restrict__ r2,
                                                f16* __restrict__ RL) {
  const int t = threadIdx.x;
  const int row = blockIdx.x * 8 + (t >> 5);
  const int lane = t & 31;
  const float4* z4 = (const float4*)(Z + (size_t)row * DIM);
  f16* rowL = RL + (size_t)row * 1024;
  float s = 0.f;
#pragma unroll
  for (int j = 0; j < 4; ++j) {
    const int e = lane + j * 32;
    const float4 v = z4[e];
    s += v.x * v.x + v.y * v.y + v.z * v.z + v.w * v.w;
    H4 hh, ll;
#pragma unroll
    for (int c = 0; c < 4; ++c) split2((&v.x)[c], hh.h[c], ll.h[c]);
    *(ushort4*)(rowL + e * 4) = hh.u;
    *(ushort4*)(rowL + 512 + e * 4) = ll.u;
  }
#pragma unroll
  for (int m = 1; m < 32; m <<= 1) s += __shfl_xor(s, m, 64);
  if (lane == 0) r2[row] = s;
}

// ---------------------------------------------------------------------------
// k_gemm: scores = residual @ cb_l^T via fp16-split MFMA (3 passes, 2 accs),
// fused dist = (r2 - 2*dot) + c2 and per-row argmin over this block's 128
// codes. Tile 64x128 (BM=64, BN=128), BK=32, 4 waves each 64x32 (1Mx4N),
// dbuf LDS 48 KB (-> 3 blocks/CU, the m97/m132 occupancy lever), round-2
// 1-barrier-per-kt loop. acc = 64 VGPR -> launch_bounds(256,3) holds.
// ---------------------------------------------------------------------------
__global__ __launch_bounds__(256, 3) void k_gemm(
    const f16* __restrict__ A,   // [BROWS][1024] interleaved limbs
    const f16* __restrict__ Bc,  // [NK][1024] interleaved limbs
    const float* __restrict__ r2v, const float* __restrict__ c2v,
    float* __restrict__ pmin, int* __restrict__ pidx) {
  __shared__ __align__(16) char smem[2][24576];  // [buf][A 8KB | B 16KB]

  const int t = threadIdx.x;
  const int lane = t & 63, wid = t >> 6;
  const int wc = wid;                          // wave owns cols [wc*32, wc*32+32)
  const int lin = blockIdx.y * 8 + blockIdx.x; // 0..4095
  const int xcd = lin & 7, kk8 = lin >> 3;     // XCD = lin%8 (round-robin)
  const int mb = xcd * 64 + (kk8 >> 3);        // bijective: 64 mb x 8 nb per XCD
  const int nb = kk8 & 7;
  const int rowBase = mb * 64, colBase = nb * 128;
  const int l15 = lane & 15, kg = lane >> 4;

  // staging: granule g (16B) -> LDS byte g*16. Slot g holds global granule
  // u = (g&7)^(r&7) of row r = g>>3; u<4 = h-limb k-granule, u>=4 = l-limb.
  // A: 512 granules (2 instr/wave), B: 1024 granules (4 instr/wave).
  const char* gA[2]; const char* gB[4];
  int ldsA[2], ldsB[4];
#pragma unroll
  for (int i = 0; i < 2; ++i) {
    const int g = i * 256 + wid * 64 + lane;
    const int r = g >> 3;                    // tile row 0..63
    const int u = (g & 7) ^ (r & 7);
    gA[i] = (const char*)A + (size_t)(rowBase + r) * 2048 +
            (size_t)(u >> 2) * 1024 + (u & 3) * 16;
    ldsA[i] = i * 4096 + wid * 1024;         // wave-uniform, [0, 8192)
  }
#pragma unroll
  for (int i = 0; i < 4; ++i) {
    const int g = i * 256 + wid * 64 + lane;
    const int r = g >> 3;                    // tile col 0..127
    const int u = (g & 7) ^ (r & 7);
    gB[i] = (const char*)Bc + (size_t)(colBase + r) * 2048 +
            (size_t)(u >> 2) * 1024 + (u & 3) * 16;
    ldsB[i] = 8192 + i * 4096 + wid * 1024;  // [8192, 24576)
  }

  const f32x4 zero = {0.f, 0.f, 0.f, 0.f};
  f32x4 accH[4][2], accL[4][2];
#pragma unroll
  for (int i = 0; i < 4; ++i)
#pragma unroll
    for (int j = 0; j < 2; ++j) { accH[i][j] = zero; accL[i][j] = zero; }

  auto stage = [&](int buf, int kt) {
    char* s = &smem[buf][0];
#pragma unroll
    for (int i = 0; i < 2; ++i) gload16(gA[i] + kt * 64, s + ldsA[i]);
#pragma unroll
    for (int i = 0; i < 4; ++i) gload16(gB[i] + kt * 64, s + ldsB[i]);
  };

  auto compute = [&](int buf) {
    const char* sA = &smem[buf][0];
    const char* sB = sA + 8192;
    f16x8 bhv[2], blv[2];
#pragma unroll
    for (int ni = 0; ni < 2; ++ni) {
      const int c = wc * 32 + ni * 16 + l15;
      const int x = c & 7;
      bhv[ni] = *(const f16x8*)(sB + c * 128 + ((kg ^ x) << 4));
      blv[ni] = *(const f16x8*)(sB + c * 128 + (((4 + kg) ^ x) << 4));
    }
#pragma unroll
    for (int mi = 0; mi < 4; ++mi) {
      const int r = mi * 16 + l15;
      const int x = r & 7;
      const f16x8 ahv = *(const f16x8*)(sA + r * 128 + ((kg ^ x) << 4));
      const f16x8 alw = *(const f16x8*)(sA + r * 128 + (((4 + kg) ^ x) << 4));
#pragma unroll
      for (int ni = 0; ni < 2; ++ni)
        accH[mi][ni] = __builtin_amdgcn_mfma_f32_16x16x32_f16(ahv, bhv[ni], accH[mi][ni], 0, 0, 0);
#pragma unroll
      for (int ni = 0; ni < 2; ++ni)
        accL[mi][ni] = __builtin_amdgcn_mfma_f32_16x16x32_f16(ahv, blv[ni], accL[mi][ni], 0, 0, 0);
#pragma unroll
      for (int ni = 0; ni < 2; ++ni)
        accL[mi][ni] = __builtin_amdgcn_mfma_f32_16x16x32_f16(alw, bhv[ni], accL[mi][ni], 0, 0, 0);
    }
  };

  stage(0, 0);
  for (int kt = 0; kt < 16; ++kt) {
    __syncthreads();                 // prev stage drained (vmcnt0 + barrier)
    if (kt < 15) stage((kt + 1) & 1, kt + 1);
    compute(kt & 1);
  }
  __syncthreads();  // drain before smem reuse in epilogue

  // Epilogue: dist + argmin. C/D layout: col = lane&15, row = (lane>>4)*4+reg.
  float* redm = (float*)&smem[0][0];           // [64][4]
  int* redi = (int*)(&smem[0][0] + 1024);      // [64][4]
  float c2c[2];
#pragma unroll
  for (int ni = 0; ni < 2; ++ni) c2c[ni] = c2v[colBase + wc * 32 + ni * 16 + l15];
#pragma unroll
  for (int mi = 0; mi < 4; ++mi) {
#pragma unroll
    for (int j = 0; j < 4; ++j) {
      const int rloc = mi * 16 + kg * 4 + j;
      const float r2r = r2v[rowBase + rloc];
      float bm = 3.4e38f; int bi = 0x7fffffff;
#pragma unroll
      for (int ni = 0; ni < 2; ++ni) {
        const int col = colBase + wc * 32 + ni * 16 + l15;
        const float dot = accH[mi][ni][j] + accL[mi][ni][j] * LSC;
        const float dist = (r2r - 2.0f * dot) + c2c[ni];  // np op order
        if (dist < bm || (dist == bm && col < bi)) { bm = dist; bi = col; }
      }
#pragma unroll
      for (int m = 1; m < 16; m <<= 1) {
        const float om = __shfl_xor(bm, m, 64);
        const int oi = __shfl_xor(bi, m, 64);
        if (om < bm || (om == bm && oi < bi)) { bm = om; bi = oi; }
      }
      if (l15 == 0) { redm[rloc * 4 + wc] = bm; redi[rloc * 4 + wc] = bi; }
    }
  }
  __syncthreads();
  if (t < 64) {
    float bm = 3.4e38f; int bi = 0x7fffffff;
#pragma unroll
    for (int x = 0; x < 4; ++x) {
      const float m = redm[t * 4 + x];
      const int i = redi[t * 4 + x];
      if (m < bm || (m == bm && i < bi)) { bm = m; bi = i; }
    }
    pmin[(size_t)nb * BROWS + rowBase + t] = bm;
    pidx[(size_t)nb * BROWS + rowBase + t] = bi;
  }
}

// ---------------------------------------------------------------------------
// k_update: finalize argmin over 8 n-block partials, gather chosen codebook
// row, write chosen into alv[l], reconstruct residual from its fp16 limbs
// (r = h + l*2^-12, error ~2^-22 relative), subtract, and rewrite the limb
// buffer in place with the NEW residual limbs (no fp32 residual staging).
// Last level: read-all-limbs-first, then write quantized = z - rn into Q
// (Q aliases the limb buffer row-for-row; per-thread read-before-write).
// ---------------------------------------------------------------------------
__global__ __launch_bounds__(256) void k_update(f16* RL,
                                                const float* __restrict__ CB,
                                                const float* __restrict__ pminv,
                                                const int* __restrict__ pidxv,
                                                float* __restrict__ chosen_out,
                                                float* __restrict__ r2out,
                                                float* __restrict__ loss,
                                                const float* __restrict__ Z,
                                                float* Q,
                                                int last) {
  __shared__ float ls[8];
  const int t = threadIdx.x;
  const int rrow = t >> 5, lane = t & 31;
  const int row = blockIdx.x * 8 + rrow;

  float bm = 3.4e38f;
  int bi = 0x7fffffff;
#pragma unroll
  for (int nbk = 0; nbk < 8; ++nbk) {
    const float m = pminv[(size_t)nbk * BROWS + row];
    const int i = pidxv[(size_t)nbk * BROWS + row];
    if (m < bm || (m == bm && i < bi)) { bm = m; bi = i; }
  }

  f16* rowL = RL + (size_t)row * 1024;
  // read-all-first: this row's residual limbs (Q write below aliases them)
  ushort4 hu[4], lu[4];
#pragma unroll
  for (int j = 0; j < 4; ++j) {
    const int e = lane + j * 32;
    hu[j] = *(const ushort4*)(rowL + e * 4);
    lu[j] = *(const ushort4*)(rowL + 512 + e * 4);
  }

  const float4* c4 = (const float4*)(CB + (size_t)bi * DIM);
  float4* ch4 = (float4*)(chosen_out + (size_t)row * DIM);
  float s = 0.f;
#pragma unroll
  for (int j = 0; j < 4; ++j) {
    const int e = lane + j * 32;
    const float4 c = c4[e];
    H4 hh, llv;
    hh.u = hu[j]; llv.u = lu[j];
    float4 rn;
    rn.x = ((float)hh.h[0] + (float)llv.h[0] * LSC) - c.x;
    rn.y = ((float)hh.h[1] + (float)llv.h[1] * LSC) - c.y;
    rn.z = ((float)hh.h[2] + (float)llv.h[2] * LSC) - c.z;
    rn.w = ((float)hh.h[3] + (float)llv.h[3] * LSC) - c.w;
    ch4[e] = c;
    if (!last) {
      H4 nh, nl;
#pragma unroll
      for (int cc = 0; cc < 4; ++cc) split2((&rn.x)[cc], nh.h[cc], nl.h[cc]);
      *(ushort4*)(rowL + e * 4) = nh.u;
      *(ushort4*)(rowL + 512 + e * 4) = nl.u;
    } else {
      const float4 zv = ((const float4*)(Z + (size_t)row * DIM))[e];
      float4 qq;
      qq.x = zv.x - rn.x; qq.y = zv.y - rn.y; qq.z = zv.z - rn.z; qq.w = zv.w - rn.w;
      ((float4*)(Q + (size_t)row * DIM))[e] = qq;
    }
    s += rn.x * rn.x + rn.y * rn.y + rn.z * rn.z + rn.w * rn.w;
  }
#pragma unroll
  for (int m = 1; m < 32; m <<= 1) s += __shfl_xor(s, m, 64);
  if (lane == 0) {
    if (!last) r2out[row] = s;
    ls[rrow] = s;
  }
  __syncthreads();
  if (t == 0) {
    float tot = 0.f;
#pragma unroll
    for (int i = 0; i < 8; ++i) tot += ls[i];
    atomicAdd(loss, tot * (1.0f / 16777216.0f));  // / (B*D) = 2^-24 exact
  }
}

// ---------------------------------------------------------------------------
extern "C" void kernel_launch(void* const* d_in, const int* in_sizes, int n_in,
                              void* d_out, int out_size, void* d_ws, size_t ws_size,
                              hipStream_t stream) {
  const float* z  = (const float*)d_in[0];   // [32768, 512]
  const float* cb = (const float*)d_in[1];   // [4, 1024, 512]

  float* q    = (float*)d_out;                                  // [B, D]
  float* alv  = (float*)d_out + (size_t)BROWS * DIM;            // [L, B, D]
  float* loss = (float*)d_out + (size_t)BROWS * DIM * (NL + 1); // scalar

  // workspace carve (~10.1 MB)
  float* c2all = (float*)d_ws;                  // [NL*NK]
  float* r2ws  = c2all + NL * NK;               // [BROWS]
  float* pmin  = r2ws + BROWS;                  // [8 * BROWS]
  int*   pidx  = (int*)(pmin + 8 * BROWS);      // [8 * BROWS]
  f16*   cbI   = (f16*)(pidx + 8 * BROWS);      // [NL*NK][1024] limbs (8 MB)

  // residual limbs live in q (64 MB, row-aliased with final Q writes)
  f16* RL = (f16*)q;                            // [BROWS][1024] interleaved

  k_pre<<<NL * NK, 64, 0, stream>>>(cb, c2all, loss, cbI);
  k_splitz<<<BROWS / 8, 256, 0, stream>>>(z, r2ws, RL);

  for (int l = 0; l < NL; ++l) {
    k_gemm<<<dim3(8, 512), 256, 0, stream>>>(RL, cbI + (size_t)l * NK * 1024,
                                             r2ws, c2all + l * NK, pmin, pidx);
    const int last = (l == NL - 1);
    k_update<<<BROWS / 8, 256, 0, stream>>>(RL, cb + (size_t)l * NK * DIM,
                                            pmin, pidx,
                                            alv + (size_t)l * BROWS * DIM,
                                            r2ws, loss, z, q, last);
  }
}

// Round 6
// 1077.202 us; speedup vs baseline: 1.0908x; 1.0908x over previous
//
#include <hip/hip_runtime.h>

#define BROWS 32768
#define DIM   512
#define NK    1024
#define NL    4

// fp16 split-GEMM: x = h + l*2^-12, h = fp16(x), l = fp16((x-h)*4096) (exact).
// dot = sum(ha*hb) + 2^-12*sum(ha*lb + la*hb); dropped la*lb ~ 2^-24 relative.
//
// Limb storage is K-TILE-MAJOR ("tiled"): granule = 8 f16 = 16 B.
//   A (residual): [mb=256][kt=16][u=8][r=128] granules; u<4 = h k-granule u,
//                 u>=4 = l k-granule u-4. Granule (mb,kt,u,r) holds limb
//                 elements [kt*32+(u&3)*8, +8) of row mb*128+r.
//   B (codebook): [lv=4][nb=8][kt=16][u=8][c=128] granules, same convention.
// => each (tile,kt) chunk is a CONTIGUOUS 16 KB blob: global_load_lds staging
// is lane-linear fully-coalesced (16 lines/instr, was 64 scattered lines),
// LDS is linear, ds_reads are granule-contiguous per quarter-wave
// (conflict-free). Fragment/MFMA semantics identical to the XOR version.
typedef _Float16 f16;
typedef _Float16 f16x8 __attribute__((ext_vector_type(8)));
typedef float f32x4 __attribute__((ext_vector_type(4)));

#define LSC 2.44140625e-4f  // 2^-12

union H4 { f16 h[4]; ushort4 u; };

__device__ __forceinline__ void split2(float x, f16& h, f16& l) {
  h = (f16)x;                           // RNE, 11-bit significand
  l = (f16)((x - (float)h) * 4096.0f);  // exact diff, exact scale
}

__device__ __forceinline__ void gload16(const void* g, const void* l) {
  __builtin_amdgcn_global_load_lds(
      (const __attribute__((address_space(1))) void*)g,
      (__attribute__((address_space(3))) void*)l, 16, 0, 0);
}

// h-piece pointer for float4-index e (elements 4e..4e+3) of local row/col rc
// within the tile whose first granule is tile_gran. l-piece = +4096 f16.
__device__ __forceinline__ f16* limb_ptr(f16* base, size_t tile_gran, int e, int rc) {
  const int kt = e >> 3, kgran = (e >> 1) & 3, half = e & 1;
  return base + (tile_gran + (size_t)kt * 1024 + kgran * 128 + rc) * 8 + half * 4;
}

// ---------------------------------------------------------------------------
// k_pre: c2 for all 4096 codes (fp32, exact) + tiled fp16 limb codebook.
// ---------------------------------------------------------------------------
__global__ __launch_bounds__(64) void k_pre(const float* __restrict__ cb,
                                            float* __restrict__ c2all,
                                            float* __restrict__ loss_slot,
                                            f16* __restrict__ cbT) {
  const int code = blockIdx.x;           // 0..4095
  const int lane = threadIdx.x;          // 0..63
  const int lv = code >> 10, k = code & 1023;
  const int nb = k >> 7, c = k & 127;
  const size_t tg = (size_t)lv * 131072 + (size_t)nb * 16384;  // granules
  const float4* c4 = (const float4*)(cb + (size_t)code * DIM);
  float s = 0.f;
#pragma unroll
  for (int j = 0; j < 2; ++j) {
    const int e = lane + j * 64;         // float4 index 0..127
    const float4 v = c4[e];
    s += v.x * v.x + v.y * v.y + v.z * v.z + v.w * v.w;
    H4 hh, ll;
#pragma unroll
    for (int q = 0; q < 4; ++q) split2((&v.x)[q], hh.h[q], ll.h[q]);
    f16* ph = limb_ptr(cbT, tg, e, c);
    *(ushort4*)ph = hh.u;
    *(ushort4*)(ph + 4096) = ll.u;
  }
#pragma unroll
  for (int m = 1; m < 64; m <<= 1) s += __shfl_xor(s, m, 64);
  if (lane == 0) c2all[code] = s;
  if (code == 0 && lane == 0) *loss_slot = 0.f;
}

// ---------------------------------------------------------------------------
// k_splitz: r2[row] = ||z_row||^2 (fp32) + tiled fp16 limbs of z.
// ---------------------------------------------------------------------------
__global__ __launch_bounds__(256) void k_splitz(const float* __restrict__ Z,
                                                float* __restrict__ r2,
                                                f16* __restrict__ RL) {
  const int t = threadIdx.x;
  const int row = blockIdx.x * 8 + (t >> 5);
  const int lane = t & 31;
  const size_t tg = (size_t)(row >> 7) * 16384;
  const int rloc = row & 127;
  const float4* z4 = (const float4*)(Z + (size_t)row * DIM);
  float s = 0.f;
#pragma unroll
  for (int j = 0; j < 4; ++j) {
    const int e = lane + j * 32;
    const float4 v = z4[e];
    s += v.x * v.x + v.y * v.y + v.z * v.z + v.w * v.w;
    H4 hh, ll;
#pragma unroll
    for (int q = 0; q < 4; ++q) split2((&v.x)[q], hh.h[q], ll.h[q]);
    f16* ph = limb_ptr(RL, tg, e, rloc);
    *(ushort4*)ph = hh.u;
    *(ushort4*)(ph + 4096) = ll.u;
  }
#pragma unroll
  for (int m = 1; m < 32; m <<= 1) s += __shfl_xor(s, m, 64);
  if (lane == 0) r2[row] = s;
}

// ---------------------------------------------------------------------------
// k_gemm: scores = residual @ cb_l^T via fp16-split MFMA (3 passes, 2 accs),
// fused dist = (r2 - 2*dot) + c2 and per-row argmin over this block's 128
// codes. Tile 128x128, BK=32, 4 waves of 64x64, dbuf LDS via global_load_lds.
// Tiled-contiguous staging: each kt stages two 16 KB blobs lane-linearly.
// ---------------------------------------------------------------------------
__global__ __launch_bounds__(256, 2) void k_gemm(
    const f16* __restrict__ A,   // tiled limbs [mb][kt][u][r]
    const f16* __restrict__ Bc,  // tiled limbs [nb][kt][u][c] (level base)
    const float* __restrict__ r2v, const float* __restrict__ c2v,
    float* __restrict__ pmin, int* __restrict__ pidx) {
  __shared__ __align__(16) char smem[2][32768];  // [buf][A 16KB | B 16KB]

  const int t = threadIdx.x;
  const int lane = t & 63, wid = t >> 6;
  const int wr = wid >> 1, wc = wid & 1;       // wave tile (64x64) in 2x2
  const int lin = blockIdx.y * 8 + blockIdx.x; // dispatch-linear id
  const int xcd = lin & 7, kk8 = lin >> 3;     // XCD = lin%8 (round-robin)
  const int mb = xcd * 32 + (kk8 >> 3);        // bijective remap
  const int nb = kk8 & 7;
  const int rowBase = mb * 128, colBase = nb * 128;
  const int l15 = lane & 15, kg = lane >> 4;

  // staging: instr (i,wid) covers 64 consecutive granules; global and LDS
  // are the SAME linear order (fully coalesced, no swizzle).
  const char* gA[4]; const char* gB[4];
  int ldsA[4], ldsB[4];
#pragma unroll
  for (int i = 0; i < 4; ++i) {
    const int s = i * 256 + wid * 64 + lane;   // granule 0..1023 within chunk
    gA[i] = (const char*)A + ((size_t)mb * 16384 + s) * 16;
    gB[i] = (const char*)Bc + ((size_t)nb * 16384 + s) * 16;
    ldsA[i] = s * 16;                          // [0, 16384)
    ldsB[i] = 16384 + s * 16;                  // [16384, 32768)
  }

  const f32x4 zero = {0.f, 0.f, 0.f, 0.f};
  f32x4 accH[4][4], accL[4][4];
#pragma unroll
  for (int i = 0; i < 4; ++i)
#pragma unroll
    for (int j = 0; j < 4; ++j) { accH[i][j] = zero; accL[i][j] = zero; }

  auto stage = [&](int buf, int kt) {
    char* s = &smem[buf][0];
    const size_t ko = (size_t)kt * 16384;      // kt stride = 1024 granules
#pragma unroll
    for (int i = 0; i < 4; ++i) {
      gload16(gA[i] + ko, s + ldsA[i]);
      gload16(gB[i] + ko, s + ldsB[i]);
    }
  };

  auto compute = [&](int buf) {
    const char* sA = &smem[buf][0];
    const char* sB = sA + 16384;
    // LDS linear layout: granule (u, rc) at byte (u*128 + rc)*16
    f16x8 bhv[4], blv[4];
#pragma unroll
    for (int ni = 0; ni < 4; ++ni) {
      const int c = wc * 64 + ni * 16 + l15;
      bhv[ni] = *(const f16x8*)(sB + (kg * 128 + c) * 16);
      blv[ni] = *(const f16x8*)(sB + ((4 + kg) * 128 + c) * 16);
    }
#pragma unroll
    for (int mi = 0; mi < 4; ++mi) {
      const int r = wr * 64 + mi * 16 + l15;
      const f16x8 ahv = *(const f16x8*)(sA + (kg * 128 + r) * 16);
      const f16x8 alw = *(const f16x8*)(sA + ((4 + kg) * 128 + r) * 16);
#pragma unroll
      for (int ni = 0; ni < 4; ++ni)
        accH[mi][ni] = __builtin_amdgcn_mfma_f32_16x16x32_f16(ahv, bhv[ni], accH[mi][ni], 0, 0, 0);
#pragma unroll
      for (int ni = 0; ni < 4; ++ni)
        accL[mi][ni] = __builtin_amdgcn_mfma_f32_16x16x32_f16(ahv, blv[ni], accL[mi][ni], 0, 0, 0);
#pragma unroll
      for (int ni = 0; ni < 4; ++ni)
        accL[mi][ni] = __builtin_amdgcn_mfma_f32_16x16x32_f16(alw, bhv[ni], accL[mi][ni], 0, 0, 0);
    }
  };

  stage(0, 0);
  for (int kt = 0; kt < 16; ++kt) {
    __syncthreads();                 // prev stage drained (vmcnt0 + barrier)
    if (kt < 15) stage((kt + 1) & 1, kt + 1);
    compute(kt & 1);
  }

  // Epilogue: dist + argmin. C/D layout: col = lane&15, row = (lane>>4)*4+reg.
  float* redm = (float*)&smem[0][0];           // [128][2]
  int* redi = (int*)(&smem[0][0] + 1024);      // [128][2]
  float c2c[4];
#pragma unroll
  for (int ni = 0; ni < 4; ++ni) c2c[ni] = c2v[colBase + wc * 64 + ni * 16 + l15];
#pragma unroll
  for (int mi = 0; mi < 4; ++mi) {
#pragma unroll
    for (int j = 0; j < 4; ++j) {
      const int rloc = wr * 64 + mi * 16 + kg * 4 + j;
      const float r2r = r2v[rowBase + rloc];
      float bm = 3.4e38f; int bi = 0x7fffffff;
#pragma unroll
      for (int ni = 0; ni < 4; ++ni) {
        const int col = colBase + wc * 64 + ni * 16 + l15;
        const float dot = accH[mi][ni][j] + accL[mi][ni][j] * LSC;
        const float dist = (r2r - 2.0f * dot) + c2c[ni];  // np op order
        if (dist < bm || (dist == bm && col < bi)) { bm = dist; bi = col; }
      }
#pragma unroll
      for (int m = 1; m < 16; m <<= 1) {
        const float om = __shfl_xor(bm, m, 64);
        const int oi = __shfl_xor(bi, m, 64);
        if (om < bm || (om == bm && oi < bi)) { bm = om; bi = oi; }
      }
      if (l15 == 0) { redm[rloc * 2 + wc] = bm; redi[rloc * 2 + wc] = bi; }
    }
  }
  __syncthreads();
  if (t < 128) {
    float bm = redm[t * 2]; int bi = redi[t * 2];
    const float m1 = redm[t * 2 + 1]; const int i1 = redi[t * 2 + 1];
    if (m1 < bm || (m1 == bm && i1 < bi)) { bm = m1; bi = i1; }
    pmin[(size_t)nb * BROWS + rowBase + t] = bm;
    pidx[(size_t)nb * BROWS + rowBase + t] = bi;
  }
}

// ---------------------------------------------------------------------------
// k_update (levels 0..2): finalize argmin over 8 n-block partials, gather
// chosen codebook row, write chosen into alv[l], reconstruct residual from
// tiled limbs (r = h + l*2^-12), subtract, rewrite limbs in place, r2 + loss.
// Level 3 (last): residual reconstructed EXACTLY as ((z-c0)-c1)-c2 from prior
// chosen (RL never read -> Q may freely overwrite the RL region);
// q = ((c0+c1)+c2)+c3 (reference summation order); loss from rn = r3-c3.
// ---------------------------------------------------------------------------
__global__ __launch_bounds__(256) void k_update(f16* RL,
                                                const float* __restrict__ CB,
                                                const float* __restrict__ pminv,
                                                const int* __restrict__ pidxv,
                                                float* __restrict__ chosen_out,
                                                float* __restrict__ r2out,
                                                float* __restrict__ loss,
                                                const float* __restrict__ Z,
                                                float* __restrict__ Q,
                                                const float* __restrict__ A0,
                                                const float* __restrict__ A1,
                                                const float* __restrict__ A2,
                                                int last) {
  __shared__ float ls[8];
  const int t = threadIdx.x;
  const int rrow = t >> 5, lane = t & 31;
  const int row = blockIdx.x * 8 + rrow;

  float bm = 3.4e38f;
  int bi = 0x7fffffff;
#pragma unroll
  for (int nbk = 0; nbk < 8; ++nbk) {
    const float m = pminv[(size_t)nbk * BROWS + row];
    const int i = pidxv[(size_t)nbk * BROWS + row];
    if (m < bm || (m == bm && i < bi)) { bm = m; bi = i; }
  }

  const size_t tg = (size_t)(row >> 7) * 16384;
  const int rloc = row & 127;
  const float4* c4 = (const float4*)(CB + (size_t)bi * DIM);
  float4* ch4 = (float4*)(chosen_out + (size_t)row * DIM);
  float s = 0.f;

  if (!last) {
#pragma unroll
    for (int j = 0; j < 4; ++j) {
      const int e = lane + j * 32;
      f16* ph = limb_ptr(RL, tg, e, rloc);
      H4 hh, llv;
      hh.u = *(const ushort4*)ph;
      llv.u = *(const ushort4*)(ph + 4096);
      const float4 c = c4[e];
      float4 rn;
      rn.x = ((float)hh.h[0] + (float)llv.h[0] * LSC) - c.x;
      rn.y = ((float)hh.h[1] + (float)llv.h[1] * LSC) - c.y;
      rn.z = ((float)hh.h[2] + (float)llv.h[2] * LSC) - c.z;
      rn.w = ((float)hh.h[3] + (float)llv.h[3] * LSC) - c.w;
      ch4[e] = c;
      H4 nh, nl;
#pragma unroll
      for (int q = 0; q < 4; ++q) split2((&rn.x)[q], nh.h[q], nl.h[q]);
      *(ushort4*)ph = nh.u;
      *(ushort4*)(ph + 4096) = nl.u;
      s += rn.x * rn.x + rn.y * rn.y + rn.z * rn.z + rn.w * rn.w;
    }
  } else {
    const float4* z4 = (const float4*)(Z + (size_t)row * DIM);
    const float4* a04 = (const float4*)(A0 + (size_t)row * DIM);
    const float4* a14 = (const float4*)(A1 + (size_t)row * DIM);
    const float4* a24 = (const float4*)(A2 + (size_t)row * DIM);
    float4* q4 = (float4*)(Q + (size_t)row * DIM);
#pragma unroll
    for (int j = 0; j < 4; ++j) {
      const int e = lane + j * 32;
      const float4 zv = z4[e];
      const float4 a0 = a04[e], a1 = a14[e], a2 = a24[e];
      const float4 c = c4[e];
      float4 r3, rn, qq;
#pragma unroll
      for (int q = 0; q < 4; ++q) {
        const float r3q = (((&zv.x)[q] - (&a0.x)[q]) - (&a1.x)[q]) - (&a2.x)[q];
        (&r3.x)[q] = r3q;
        (&rn.x)[q] = r3q - (&c.x)[q];
        (&qq.x)[q] = (((&a0.x)[q] + (&a1.x)[q]) + (&a2.x)[q]) + (&c.x)[q];
      }
      ch4[e] = c;
      q4[e] = qq;
      s += rn.x * rn.x + rn.y * rn.y + rn.z * rn.z + rn.w * rn.w;
    }
  }
#pragma unroll
  for (int m = 1; m < 32; m <<= 1) s += __shfl_xor(s, m, 64);
  if (lane == 0) {
    if (!last) r2out[row] = s;
    ls[rrow] = s;
  }
  __syncthreads();
  if (t == 0) {
    float tot = 0.f;
#pragma unroll
    for (int i = 0; i < 8; ++i) tot += ls[i];
    atomicAdd(loss, tot * (1.0f / 16777216.0f));  // / (B*D) = 2^-24 exact
  }
}

// ---------------------------------------------------------------------------
extern "C" void kernel_launch(void* const* d_in, const int* in_sizes, int n_in,
                              void* d_out, int out_size, void* d_ws, size_t ws_size,
                              hipStream_t stream) {
  const float* z  = (const float*)d_in[0];   // [32768, 512]
  const float* cb = (const float*)d_in[1];   // [4, 1024, 512]

  float* q    = (float*)d_out;                                  // [B, D]
  float* alv  = (float*)d_out + (size_t)BROWS * DIM;            // [L, B, D]
  float* loss = (float*)d_out + (size_t)BROWS * DIM * (NL + 1); // scalar

  // workspace carve (~10.1 MB)
  float* c2all = (float*)d_ws;                  // [NL*NK]
  float* r2ws  = c2all + NL * NK;               // [BROWS]
  float* pmin  = r2ws + BROWS;                  // [8 * BROWS]
  int*   pidx  = (int*)(pmin + 8 * BROWS);      // [8 * BROWS]
  f16*   cbT   = (f16*)(pidx + 8 * BROWS);      // tiled limbs, 8 MB

  // residual limbs live in q (64 MB); last-level update never reads RL, so
  // Q writes are race-free.
  f16* RL = (f16*)q;

  k_pre<<<NL * NK, 64, 0, stream>>>(cb, c2all, loss, cbT);
  k_splitz<<<BROWS / 8, 256, 0, stream>>>(z, r2ws, RL);

  for (int l = 0; l < NL; ++l) {
    k_gemm<<<dim3(8, 256), 256, 0, stream>>>(
        RL, cbT + (size_t)l * 131072 * 8,
        r2ws, c2all + l * NK, pmin, pidx);
    const int last = (l == NL - 1);
    k_update<<<BROWS / 8, 256, 0, stream>>>(
        RL, cb + (size_t)l * NK * DIM, pmin, pidx,
        alv + (size_t)l * BROWS * DIM, r2ws, loss, z, q,
        alv + 0 * (size_t)BROWS * DIM,
        alv + 1 * (size_t)BROWS * DIM,
        alv + 2 * (size_t)BROWS * DIM, last);
  }
}